// Round 5
// baseline (1347.596 us; speedup 1.0000x reference)
//
#include <hip/hip_runtime.h>
#include <hip/hip_bf16.h>

// SwiGLU FFN, fp32 in/out: out = clamp(silu(x@w1t) * (x@w3t), ±65504) @ w2t
// x[8192,3072], w13[16384,3072] (rows 0..8191 = w3 -> x3, 8192.. = w1 -> x1), w2[3072,8192].
// bf16 compute via cvt pre-pass; mfma_f32_32x32x16_bf16; fp32 accum; fp32 out.
// Round-5: race FIX (vmcnt -> s_barrier -> ds_reads), 4-buf depth-3 pipeline (gateup),
// 3-buf depth-2 (down), single barrier per K-tile, improved BK=32 swizzle ((row>>1)&3).
// Swizzle rule #21: pre-swizzled global source + linear gload_lds dest + swizzled ds_read.

typedef __attribute__((ext_vector_type(8))) __bf16 bf16x8;
typedef __attribute__((ext_vector_type(16))) float f32x16;

#define GLD_LDS16(gptr, lptr)                                                        \
  __builtin_amdgcn_global_load_lds(                                                  \
      (const __attribute__((address_space(1))) void*)(gptr),                         \
      (__attribute__((address_space(3))) void*)(lptr), 16, 0, 0)

#define VMCNT(n) asm volatile("s_waitcnt vmcnt(" #n ")" ::: "memory")
#define FENCE()  asm volatile("" ::: "memory")

__device__ __forceinline__ __bf16 bfr(float f) {  // RNE fp32->bf16
  unsigned int u = __builtin_bit_cast(unsigned int, f);
  unsigned short r = (unsigned short)((u + 0x7FFFu + ((u >> 16) & 1u)) >> 16);
  return __builtin_bit_cast(__bf16, r);
}

// ---------------- fp32 -> bf16 conversion pre-pass ----------------
__global__ __launch_bounds__(256)
void k_cvt(const float* __restrict__ src, unsigned short* __restrict__ dst, long n) {
  long i = ((long)blockIdx.x * 256 + threadIdx.x) * 8;
  const long stride = (long)gridDim.x * 256 * 8;
  for (; i < n; i += stride) {
    float4 f0 = *(const float4*)(src + i);
    float4 f1 = *(const float4*)(src + i + 4);
    bf16x8 o;
    o[0] = bfr(f0.x); o[1] = bfr(f0.y); o[2] = bfr(f0.z); o[3] = bfr(f0.w);
    o[4] = bfr(f1.x); o[5] = bfr(f1.y); o[6] = bfr(f1.z); o[7] = bfr(f1.w);
    *(bf16x8*)(dst + i) = o;
  }
}

// ============ Kernel 1: fused gate/up, 256x128 G-tile, BK=32, 4-buf depth-3 ============
// 8 waves (2M x 4N), per-wave 128x32 per op, 32x32x16 frags: 12 ds_read + 16 MFMA / K-tile.
__global__ __launch_bounds__(512, 2)
void k_gateup10(const unsigned short* __restrict__ X,
                const unsigned short* __restrict__ W13,
                __hip_bfloat16* __restrict__ G)
{
  constexpr int K = 3072, LDG = 8192, NT = K / 32;
  __shared__ unsigned short lds[4 * 16384];  // 128 KB; buf: A[256][32] | B3[128][32] | B1[128][32]

  const int t = threadIdx.x;
  const int l = t & 63, wid = t >> 6;
  const int wm = wid >> 2, wn = wid & 3;     // 2M x 4N
  const int l31 = l & 31, lh = l >> 5;
  const int sw2 = (l31 >> 1) & 3;            // BK=32 read swizzle

  const int bid = blockIdx.x;                // 2048 blocks, XCD-chunked
  const int swz = (bid & 7) * 256 + (bid >> 3);
  const int mb = swz >> 6, nb = swz & 63;

  const int srow = t >> 2;                              // 0..127 (4 lanes/row, 64B rows)
  const int scol = ((t & 3) ^ ((srow >> 1) & 3)) * 8;   // pre-swizzled global slot
  const unsigned short* xa = X   + (size_t)(mb * 256 + srow) * K + scol;
  const unsigned short* b3 = W13 + (size_t)(nb * 128 + srow) * K + scol;
  const unsigned short* b1 = W13 + (size_t)(8192 + nb * 128 + srow) * K + scol;
  const int lo = t * 8;

  f32x16 acc3[4], acc1[4];
#pragma unroll
  for (int mf = 0; mf < 4; ++mf)
#pragma unroll
    for (int r = 0; r < 16; ++r) { acc3[mf][r] = 0.f; acc1[mf][r] = 0.f; }

  // prologue: stage tiles 0,1,2 (4 loads each)
#pragma unroll
  for (int tt = 0; tt < 3; ++tt) {
    unsigned short* S = lds + tt * 16384;
    const int kt = tt * 32;
    GLD_LDS16(xa + kt, S + lo);
    GLD_LDS16(xa + (size_t)128 * K + kt, S + 4096 + lo);
    GLD_LDS16(b3 + kt, S + 8192 + lo);
    GLD_LDS16(b1 + kt, S + 12288 + lo);
  }

  for (int tk = 0; tk < NT; ++tk) {
    unsigned short* A = lds + (tk & 3) * 16384;
    unsigned short* S = lds + ((tk + 3) & 3) * 16384;   // tile tk-1's buffer (reads done)
    const int ksrc = (tk + 3 < NT ? tk + 3 : 0) * 32;   // wrap: uniform load count

    VMCNT(8);                        // own tile-tk loads landed (tk+1,tk+2 in flight)
    __builtin_amdgcn_s_barrier();    // ⇒ ALL waves' tile-tk loads landed
    FENCE();

    bf16x8 ra[4][2], r3[2], r1[2];
#pragma unroll
    for (int mf = 0; mf < 4; ++mf)
#pragma unroll
      for (int ks = 0; ks < 2; ++ks) {
        const int row = wm * 128 + mf * 32 + l31;
        ra[mf][ks] = *(const bf16x8*)(A + row * 32 + (((ks * 2 + lh) ^ sw2) * 8));
      }
#pragma unroll
    for (int ks = 0; ks < 2; ++ks) {
      const int row = wn * 32 + l31;
      const int sl = ((ks * 2 + lh) ^ sw2) * 8;
      r3[ks] = *(const bf16x8*)(A + 8192 + row * 32 + sl);
      r1[ks] = *(const bf16x8*)(A + 12288 + row * 32 + sl);
    }

    // stage tile tk+3 into tile tk-1's buffer (safe: all waves' tk-1 reads
    // completed before they arrived at this iteration's barrier)
    GLD_LDS16(xa + ksrc, S + lo);
    GLD_LDS16(xa + (size_t)128 * K + ksrc, S + 4096 + lo);
    GLD_LDS16(b3 + ksrc, S + 8192 + lo);
    GLD_LDS16(b1 + ksrc, S + 12288 + lo);

    __builtin_amdgcn_s_setprio(1);
#pragma unroll
    for (int ks = 0; ks < 2; ++ks)
#pragma unroll
      for (int mf = 0; mf < 4; ++mf) {
        acc3[mf] = __builtin_amdgcn_mfma_f32_32x32x16_bf16(ra[mf][ks], r3[ks], acc3[mf], 0, 0, 0);
        acc1[mf] = __builtin_amdgcn_mfma_f32_32x32x16_bf16(ra[mf][ks], r1[ks], acc1[mf], 0, 0, 0);
      }
    __builtin_amdgcn_s_setprio(0);
  }

  // epilogue: g = clamp(silu(x1)*x3). 32x32 C/D: col=l&31, row=(r&3)+8*(r>>2)+4*(l>>5)
  const int gr0 = mb * 256 + wm * 128;
  const int gc  = nb * 128 + wn * 32 + l31;
#pragma unroll
  for (int mf = 0; mf < 4; ++mf)
#pragma unroll
    for (int r = 0; r < 16; ++r) {
      const int row = gr0 + mf * 32 + (r & 3) + 8 * (r >> 2) + 4 * lh;
      float h3 = acc3[mf][r], h1 = acc1[mf][r];
      float s  = h1 / (1.f + __expf(-h1));
      float g  = fminf(fmaxf(s * h3, -65504.f), 65504.f);
      G[(size_t)row * LDG + gc] = __float2bfloat16(g);
    }
}

// ============ Kernel 2: down proj, 256x128 tile, BK=64, 3-buf depth-2 ============
// 8 waves (4M x 2N), per-wave 64x64, 32x32x16 frags: 16 ds_read + 16 MFMA / K-tile.
__global__ __launch_bounds__(512, 2)
void k_down10(const unsigned short* __restrict__ Gm,
              const unsigned short* __restrict__ W2,
              float* __restrict__ Out)
{
  constexpr int K = 8192, LDO = 3072, NT = K / 64;
  __shared__ unsigned short lds[3 * 24576];  // 144 KB; buf: A[256][64] | B[128][64]

  const int t = threadIdx.x;
  const int l = t & 63, wid = t >> 6;
  const int wm = wid >> 1, wn = wid & 1;     // 4M x 2N
  const int l31 = l & 31, lh = l >> 5;
  const int sw = l31 & 7;                    // BK=64 read swizzle

  const int bid = blockIdx.x;                // 768 blocks
  const int swz = (bid & 7) * 96 + (bid >> 3);
  const int mb = swz / 24, nb = swz % 24;

  const int srow = t >> 3;                      // 0..63 (8 lanes/row, 128B rows)
  const int scol = ((t & 7) ^ (srow & 7)) * 8;
  const unsigned short* ga = Gm + (size_t)(mb * 256 + srow) * K + scol;
  const unsigned short* wb = W2 + (size_t)(nb * 128 + srow) * K + scol;
  const int lo = t * 8;

  f32x16 acc[2][2];
#pragma unroll
  for (int mf = 0; mf < 2; ++mf)
#pragma unroll
    for (int nf = 0; nf < 2; ++nf)
#pragma unroll
      for (int r = 0; r < 16; ++r) acc[mf][nf][r] = 0.f;

  // prologue: tiles 0,1 (6 loads each)
#pragma unroll
  for (int tt = 0; tt < 2; ++tt) {
    unsigned short* S = lds + tt * 24576;
    const int kt = tt * 64;
#pragma unroll
    for (int q = 0; q < 4; ++q)
      GLD_LDS16(ga + (size_t)(q * 64) * K + kt, S + q * 4096 + lo);
#pragma unroll
    for (int h = 0; h < 2; ++h)
      GLD_LDS16(wb + (size_t)(h * 64) * K + kt, S + 16384 + h * 4096 + lo);
  }

  for (int tk = 0; tk < NT; ++tk) {
    unsigned short* A = lds + (tk % 3) * 24576;
    unsigned short* S = lds + ((tk + 2) % 3) * 24576;  // tile tk-1's buffer
    const int ksrc = (tk + 2 < NT ? tk + 2 : 0) * 64;

    VMCNT(6);                        // own tile-tk loads landed (tk+1 in flight)
    __builtin_amdgcn_s_barrier();    // ⇒ ALL waves' tile-tk loads landed
    FENCE();

    bf16x8 ra[2][4], rb[2][4];
#pragma unroll
    for (int mf = 0; mf < 2; ++mf)
#pragma unroll
      for (int ks = 0; ks < 4; ++ks) {
        const int row = wm * 64 + mf * 32 + l31;
        ra[mf][ks] = *(const bf16x8*)(A + row * 64 + (((ks * 2 + lh) ^ sw) * 8));
      }
#pragma unroll
    for (int nf = 0; nf < 2; ++nf)
#pragma unroll
      for (int ks = 0; ks < 4; ++ks) {
        const int row = wn * 64 + nf * 32 + l31;
        rb[nf][ks] = *(const bf16x8*)(A + 16384 + row * 64 + (((ks * 2 + lh) ^ sw) * 8));
      }

    // stage tile tk+2 into tile tk-1's buffer (safe per barrier argument)
#pragma unroll
    for (int q = 0; q < 4; ++q)
      GLD_LDS16(ga + (size_t)(q * 64) * K + ksrc, S + q * 4096 + lo);
#pragma unroll
    for (int h = 0; h < 2; ++h)
      GLD_LDS16(wb + (size_t)(h * 64) * K + ksrc, S + 16384 + h * 4096 + lo);

    __builtin_amdgcn_s_setprio(1);
#pragma unroll
    for (int ks = 0; ks < 4; ++ks)
#pragma unroll
      for (int mf = 0; mf < 2; ++mf)
#pragma unroll
        for (int nf = 0; nf < 2; ++nf)
          acc[mf][nf] = __builtin_amdgcn_mfma_f32_32x32x16_bf16(ra[mf][ks], rb[nf][ks], acc[mf][nf], 0, 0, 0);
    __builtin_amdgcn_s_setprio(0);
  }

  const int r0 = mb * 256 + wm * 64;
  const int c0 = nb * 128 + wn * 64;
#pragma unroll
  for (int mf = 0; mf < 2; ++mf)
#pragma unroll
    for (int nf = 0; nf < 2; ++nf)
#pragma unroll
      for (int r = 0; r < 16; ++r) {
        const int row = r0 + mf * 32 + (r & 3) + 8 * (r >> 2) + 4 * lh;
        Out[(size_t)row * LDO + c0 + nf * 32 + l31] = acc[mf][nf][r];
      }
}

extern "C" void kernel_launch(void* const* d_in, const int* in_sizes, int n_in,
                              void* d_out, int out_size, void* d_ws, size_t ws_size,
                              hipStream_t stream) {
  const float* x   = (const float*)d_in[0];   // [2,4096,3072] f32
  const float* w13 = (const float*)d_in[1];   // [16384,3072] f32
  const float* w2  = (const float*)d_in[2];   // [3072,8192] f32
  float* out = (float*)d_out;                 // [2,4096,3072] f32

  const long NX = 25165824L, NW13 = 50331648L, NW2 = 25165824L;
  const size_t XB = 50331648, W13B = 100663296, W2B = 50331648;

  unsigned short* xb   = (unsigned short*)d_ws;
  unsigned short* w13b = (unsigned short*)((char*)d_ws + XB);
  unsigned short* w2b  = (unsigned short*)((char*)d_ws + XB + W13B);
  __hip_bfloat16* g    = (__hip_bfloat16*)((char*)d_ws + XB + W13B + W2B);

  k_cvt<<<2048, 256, 0, stream>>>(x,   xb,   NX);
  k_cvt<<<2048, 256, 0, stream>>>(w13, w13b, NW13);
  k_cvt<<<2048, 256, 0, stream>>>(w2,  w2b,  NW2);
  k_gateup10<<<2048, 512, 0, stream>>>(xb, w13b, g);
  k_down10<<<768, 512, 0, stream>>>((const unsigned short*)g, w2b, out);
}

// Round 6
// 1194.970 us; speedup vs baseline: 1.1277x; 1.1277x over previous
//
#include <hip/hip_runtime.h>
#include <hip/hip_bf16.h>

// SwiGLU FFN, fp32 in/out: out = clamp(silu(x@w1t) * (x@w3t), ±65504) @ w2t
// x[8192,3072], w13[16384,3072] (rows 0..8191 = w3 -> x3, 8192.. = w1 -> x1), w2[3072,8192].
// bf16 compute via cvt pre-pass; mfma_f32_16x16x32_bf16 (R2/R3-proven layouts);
// fp32 accum; fp32 out.
// Round-6: BK=64 + row&7 swizzle everywhere (0-conflict, proven). Gateup = m201-style
// 4-phase/K-tile with per-phase half-stage + counted VMCNT(6) once per K-tile.
// Down = R5-proven 1-phase/3-buf/VMCNT(6) skeleton with 16x16 frags.
// Swizzle rule #21: pre-swizzled global source + linear gload_lds dest + swizzled ds_read.

typedef __attribute__((ext_vector_type(8))) __bf16 bf16x8;
typedef __attribute__((ext_vector_type(4))) float f32x4;

#define GLD_LDS16(gptr, lptr)                                                        \
  __builtin_amdgcn_global_load_lds(                                                  \
      (const __attribute__((address_space(1))) void*)(gptr),                         \
      (__attribute__((address_space(3))) void*)(lptr), 16, 0, 0)

#define VMCNT(n) asm volatile("s_waitcnt vmcnt(" #n ")" ::: "memory")
#define BAR()    __builtin_amdgcn_s_barrier()

#define MFMA16(a, b, c) __builtin_amdgcn_mfma_f32_16x16x32_bf16((a), (b), (c), 0, 0, 0)

__device__ __forceinline__ __bf16 bfr(float f) {  // RNE fp32->bf16
  unsigned int u = __builtin_bit_cast(unsigned int, f);
  unsigned short r = (unsigned short)((u + 0x7FFFu + ((u >> 16) & 1u)) >> 16);
  return __builtin_bit_cast(__bf16, r);
}

// ---------------- fp32 -> bf16 conversion pre-pass ----------------
__global__ __launch_bounds__(256)
void k_cvt(const float* __restrict__ src, unsigned short* __restrict__ dst, long n) {
  long i = ((long)blockIdx.x * 256 + threadIdx.x) * 8;
  const long stride = (long)gridDim.x * 256 * 8;
  for (; i < n; i += stride) {
    float4 f0 = *(const float4*)(src + i);
    float4 f1 = *(const float4*)(src + i + 4);
    bf16x8 o;
    o[0] = bfr(f0.x); o[1] = bfr(f0.y); o[2] = bfr(f0.z); o[3] = bfr(f0.w);
    o[4] = bfr(f1.x); o[5] = bfr(f1.y); o[6] = bfr(f1.z); o[7] = bfr(f1.w);
    *(bf16x8*)(dst + i) = o;
  }
}

// ============ Kernel 1: fused gate/up, 256x128 g-tile, BK=64, 2-dbuf, 4-phase ============
// 8 waves (2M x 4N), per-wave 128 rows x (32 B3-cols + 32 B1-cols). 16x16x32 frags.
// Per K-tile: P1{rd A-mq0(8)+B3(4); st Aq13(c+1); bar; 16 MFMA acc3-lo; bar}
//             P2{rd B1(4); st B3(c+2); bar; 16 MFMA acc1-lo; bar}
//             P3{rd A-mq1(8); st Aq02(c+2); bar; 16 MFMA acc3-hi; bar}
//             P4{st B1(c+2); VMCNT(6); bar; 16 MFMA acc1-hi; bar}
__global__ __launch_bounds__(512, 2)
void k_gateup11(const unsigned short* __restrict__ X,
                const unsigned short* __restrict__ W13,
                __hip_bfloat16* __restrict__ G)
{
  constexpr int K = 3072, LDG = 8192, NT = K / 64;
  __shared__ unsigned short lds[65536];  // 128KB: A[2]@0 (16384 ea) | B3[2]@32768 (8192) | B1[2]@49152

  const int t = threadIdx.x, l = t & 63, wid = t >> 6;
  const int wm = wid >> 2, wn = wid & 3;          // 2M x 4N
  const int l15 = l & 15, lhi = l >> 4, sw = l15 & 7;

  const int bid = blockIdx.x;                     // 2048 blocks, XCD-chunked
  const int swz = (bid & 7) * 256 + (bid >> 3);
  const int mb = swz >> 6, nb = swz & 63;

  const int srow = t >> 3;                        // 0..63
  const int scol = ((t & 7) ^ (srow & 7)) * 8;    // pre-swizzled global slot
  const unsigned short* xa = X   + (size_t)(mb * 256 + srow) * K + scol;
  const unsigned short* b3 = W13 + (size_t)(nb * 128 + srow) * K + scol;
  const unsigned short* b1 = W13 + (size_t)(8192 + nb * 128 + srow) * K + scol;
  const int lo = t * 8;

#define ST_A02(d, kt) do {                                                     \
    GLD_LDS16(xa + (kt),                 lds + (d) * 16384 + lo);              \
    GLD_LDS16(xa + (size_t)128 * K + (kt), lds + (d) * 16384 + 8192 + lo);     \
  } while (0)
#define ST_A13(d, kt) do {                                                     \
    GLD_LDS16(xa + (size_t)64 * K + (kt),  lds + (d) * 16384 + 4096 + lo);     \
    GLD_LDS16(xa + (size_t)192 * K + (kt), lds + (d) * 16384 + 12288 + lo);    \
  } while (0)
#define ST_B3(d, kt) do {                                                      \
    GLD_LDS16(b3 + (kt),                lds + 32768 + (d) * 8192 + lo);        \
    GLD_LDS16(b3 + (size_t)64 * K + (kt), lds + 32768 + (d) * 8192 + 4096 + lo); \
  } while (0)
#define ST_B1(d, kt) do {                                                      \
    GLD_LDS16(b1 + (kt),                lds + 49152 + (d) * 8192 + lo);        \
    GLD_LDS16(b1 + (size_t)64 * K + (kt), lds + 49152 + (d) * 8192 + 4096 + lo); \
  } while (0)

  f32x4 acc3[8][2], acc1[8][2];
#pragma unroll
  for (int m = 0; m < 8; ++m)
#pragma unroll
    for (int n = 0; n < 2; ++n) {
      acc3[m][n] = (f32x4){0.f, 0.f, 0.f, 0.f};
      acc1[m][n] = (f32x4){0.f, 0.f, 0.f, 0.f};
    }

  // prologue: tile0 full (8 loads, steady-state order), tile1 first 6
  ST_B3(0, 0); ST_A02(0, 0); ST_B1(0, 0); ST_A13(0, 0);
  ST_B3(1, 64); ST_A02(1, 64); ST_B1(1, 64);
  VMCNT(6);            // tile0's 8 landed; tile1's 6 in flight
  BAR();

  for (int c = 0; c < NT; ++c) {
    const int d = c & 1, dn = d ^ 1;
    const int k1 = (c + 1 < NT ? c + 1 : 0) * 64;
    const int k2 = (c + 2 < NT ? c + 2 : 0) * 64;
    const int Ab = d * 16384, B3b = 32768 + d * 8192, B1b = 49152 + d * 8192;

    bf16x8 ra[4][2], rb[4][2], r3[2][2], r1[2][2];

    // ---- P1: read A-mq0 + B3; stage A-q1q3(c+1); MFMA acc3 lo ----
#pragma unroll
    for (int mf = 0; mf < 4; ++mf)
#pragma unroll
      for (int kk = 0; kk < 2; ++kk)
        ra[mf][kk] = *(const bf16x8*)(lds + Ab + (wm * 128 + mf * 16 + l15) * 64 + ((kk * 4 + lhi) ^ sw) * 8);
#pragma unroll
    for (int nf = 0; nf < 2; ++nf)
#pragma unroll
      for (int kk = 0; kk < 2; ++kk)
        r3[nf][kk] = *(const bf16x8*)(lds + B3b + (wn * 32 + nf * 16 + l15) * 64 + ((kk * 4 + lhi) ^ sw) * 8);
    ST_A13(dn, k1);
    BAR();
    __builtin_amdgcn_s_setprio(1);
#pragma unroll
    for (int mf = 0; mf < 4; ++mf)
#pragma unroll
      for (int nf = 0; nf < 2; ++nf)
#pragma unroll
        for (int kk = 0; kk < 2; ++kk)
          acc3[mf][nf] = MFMA16(ra[mf][kk], r3[nf][kk], acc3[mf][nf]);
    __builtin_amdgcn_s_setprio(0);
    BAR();

    // ---- P2: read B1; stage B3(c+2); MFMA acc1 lo ----
#pragma unroll
    for (int nf = 0; nf < 2; ++nf)
#pragma unroll
      for (int kk = 0; kk < 2; ++kk)
        r1[nf][kk] = *(const bf16x8*)(lds + B1b + (wn * 32 + nf * 16 + l15) * 64 + ((kk * 4 + lhi) ^ sw) * 8);
    ST_B3(d, k2);
    BAR();
    __builtin_amdgcn_s_setprio(1);
#pragma unroll
    for (int mf = 0; mf < 4; ++mf)
#pragma unroll
      for (int nf = 0; nf < 2; ++nf)
#pragma unroll
        for (int kk = 0; kk < 2; ++kk)
          acc1[mf][nf] = MFMA16(ra[mf][kk], r1[nf][kk], acc1[mf][nf]);
    __builtin_amdgcn_s_setprio(0);
    BAR();

    // ---- P3: read A-mq1; stage A-q0q2(c+2); MFMA acc3 hi (reuse r3) ----
#pragma unroll
    for (int mf = 0; mf < 4; ++mf)
#pragma unroll
      for (int kk = 0; kk < 2; ++kk)
        rb[mf][kk] = *(const bf16x8*)(lds + Ab + (wm * 128 + 64 + mf * 16 + l15) * 64 + ((kk * 4 + lhi) ^ sw) * 8);
    ST_A02(d, k2);
    BAR();
    __builtin_amdgcn_s_setprio(1);
#pragma unroll
    for (int mf = 0; mf < 4; ++mf)
#pragma unroll
      for (int nf = 0; nf < 2; ++nf)
#pragma unroll
        for (int kk = 0; kk < 2; ++kk)
          acc3[4 + mf][nf] = MFMA16(rb[mf][kk], r3[nf][kk], acc3[4 + mf][nf]);
    __builtin_amdgcn_s_setprio(0);
    BAR();

    // ---- P4: stage B1(c+2); VMCNT(6) => tile c+1 fully landed; MFMA acc1 hi ----
    ST_B1(d, k2);
    VMCNT(6);
    BAR();
    __builtin_amdgcn_s_setprio(1);
#pragma unroll
    for (int mf = 0; mf < 4; ++mf)
#pragma unroll
      for (int nf = 0; nf < 2; ++nf)
#pragma unroll
        for (int kk = 0; kk < 2; ++kk)
          acc1[4 + mf][nf] = MFMA16(rb[mf][kk], r1[nf][kk], acc1[4 + mf][nf]);
    __builtin_amdgcn_s_setprio(0);
    BAR();
  }

  // epilogue: g = clamp(silu(x1)*x3). 16x16 C/D: col=l15, row=lhi*4+r
  const int gr0 = mb * 256 + wm * 128;
  const int gc0 = nb * 128 + wn * 32;
#pragma unroll
  for (int mf = 0; mf < 8; ++mf) {
    const int ro = (mf >> 2) * 64 + (mf & 3) * 16;
#pragma unroll
    for (int nf = 0; nf < 2; ++nf)
#pragma unroll
      for (int r = 0; r < 4; ++r) {
        float h3 = acc3[mf][nf][r];
        float h1 = acc1[mf][nf][r];
        float s  = h1 / (1.f + __expf(-h1));
        float g  = fminf(fmaxf(s * h3, -65504.f), 65504.f);
        G[(size_t)(gr0 + ro + lhi * 4 + r) * LDG + (gc0 + nf * 16 + l15)] =
            __float2bfloat16(g);
      }
  }
#undef ST_A02
#undef ST_A13
#undef ST_B3
#undef ST_B1
}

// ============ Kernel 2: down proj, 256x128 tile, BK=64, 3-buf, 1 phase/K-tile ============
// 8 waves (4M x 2N), per-wave 64x64, 16x16x32 frags: 16 ds_read + 32 MFMA per K-tile.
// R5-proven skeleton: VMCNT(6); BAR; reads; stage(c+2); prio MFMA.
__global__ __launch_bounds__(512, 2)
void k_down11(const unsigned short* __restrict__ Gm,
              const unsigned short* __restrict__ W2,
              float* __restrict__ Out)
{
  constexpr int K = 8192, LDO = 3072, NT = K / 64;
  __shared__ unsigned short lds[73728];  // 144KB: A[3]@0 (16384 ea) | B[3]@49152 (8192 ea)

  const int t = threadIdx.x, l = t & 63, wid = t >> 6;
  const int wm = wid >> 1, wn = wid & 1;          // 4M x 2N
  const int l15 = l & 15, lhi = l >> 4, sw = l15 & 7;

  const int bid = blockIdx.x;                     // 768 blocks
  const int swz = (bid & 7) * 96 + (bid >> 3);
  const int mb = swz / 24, nb = swz % 24;

  const int srow = t >> 3;
  const int scol = ((t & 7) ^ (srow & 7)) * 8;
  const unsigned short* ga = Gm + (size_t)(mb * 256 + srow) * K + scol;
  const unsigned short* wb = W2 + (size_t)(nb * 128 + srow) * K + scol;
  const int lo = t * 8;

#define DST_A(e, kt) do {                                                       \
    GLD_LDS16(ga + (kt),                 lds + (e) * 16384 + lo);               \
    GLD_LDS16(ga + (size_t)64 * K + (kt),  lds + (e) * 16384 + 4096 + lo);      \
    GLD_LDS16(ga + (size_t)128 * K + (kt), lds + (e) * 16384 + 8192 + lo);      \
    GLD_LDS16(ga + (size_t)192 * K + (kt), lds + (e) * 16384 + 12288 + lo);     \
  } while (0)
#define DST_B(e, kt) do {                                                       \
    GLD_LDS16(wb + (kt),                lds + 49152 + (e) * 8192 + lo);         \
    GLD_LDS16(wb + (size_t)64 * K + (kt), lds + 49152 + (e) * 8192 + 4096 + lo); \
  } while (0)

  f32x4 acc[4][4];
#pragma unroll
  for (int mf = 0; mf < 4; ++mf)
#pragma unroll
    for (int nf = 0; nf < 4; ++nf)
      acc[mf][nf] = (f32x4){0.f, 0.f, 0.f, 0.f};

  // prologue: tiles 0,1 (6 loads each)
  DST_B(0, 0);  DST_A(0, 0);
  DST_B(1, 64); DST_A(1, 64);

  for (int c = 0; c < NT; ++c) {
    const int e = c % 3;
    const int eS = (c + 2) % 3;
    const int k2 = (c + 2 < NT ? c + 2 : 0) * 64;

    VMCNT(6);    // tile c's 6 landed (tile c+1's 6 in flight)
    BAR();

    bf16x8 ra[4][2], rb[4][2];
#pragma unroll
    for (int mf = 0; mf < 4; ++mf)
#pragma unroll
      for (int kk = 0; kk < 2; ++kk)
        ra[mf][kk] = *(const bf16x8*)(lds + e * 16384 + (wm * 64 + mf * 16 + l15) * 64 + ((kk * 4 + lhi) ^ sw) * 8);
#pragma unroll
    for (int nf = 0; nf < 4; ++nf)
#pragma unroll
      for (int kk = 0; kk < 2; ++kk)
        rb[nf][kk] = *(const bf16x8*)(lds + 49152 + e * 8192 + (wn * 64 + nf * 16 + l15) * 64 + ((kk * 4 + lhi) ^ sw) * 8);

    // stage tile c+2 into buffer of tile c-1 (reads done before this iter's barrier)
    DST_B(eS, k2);
    DST_A(eS, k2);

    __builtin_amdgcn_s_setprio(1);
#pragma unroll
    for (int mf = 0; mf < 4; ++mf)
#pragma unroll
      for (int nf = 0; nf < 4; ++nf)
#pragma unroll
        for (int kk = 0; kk < 2; ++kk)
          acc[mf][nf] = MFMA16(ra[mf][kk], rb[nf][kk], acc[mf][nf]);
    __builtin_amdgcn_s_setprio(0);
  }

  const int r0 = mb * 256 + wm * 64;
  const int c0 = nb * 128 + wn * 64;
#pragma unroll
  for (int mf = 0; mf < 4; ++mf)
#pragma unroll
    for (int nf = 0; nf < 4; ++nf)
#pragma unroll
      for (int r = 0; r < 4; ++r)
        Out[(size_t)(r0 + mf * 16 + lhi * 4 + r) * LDO + (c0 + nf * 16 + l15)] =
            acc[mf][nf][r];
#undef DST_A
#undef DST_B
}

extern "C" void kernel_launch(void* const* d_in, const int* in_sizes, int n_in,
                              void* d_out, int out_size, void* d_ws, size_t ws_size,
                              hipStream_t stream) {
  const float* x   = (const float*)d_in[0];   // [2,4096,3072] f32
  const float* w13 = (const float*)d_in[1];   // [16384,3072] f32
  const float* w2  = (const float*)d_in[2];   // [3072,8192] f32
  float* out = (float*)d_out;                 // [2,4096,3072] f32

  const long NX = 25165824L, NW13 = 50331648L, NW2 = 25165824L;
  const size_t XB = 50331648, W13B = 100663296, W2B = 50331648;

  unsigned short* xb   = (unsigned short*)d_ws;
  unsigned short* w13b = (unsigned short*)((char*)d_ws + XB);
  unsigned short* w2b  = (unsigned short*)((char*)d_ws + XB + W13B);
  __hip_bfloat16* g    = (__hip_bfloat16*)((char*)d_ws + XB + W13B + W2B);

  k_cvt<<<2048, 256, 0, stream>>>(x,   xb,   NX);
  k_cvt<<<2048, 256, 0, stream>>>(w13, w13b, NW13);
  k_cvt<<<2048, 256, 0, stream>>>(w2,  w2b,  NW2);
  k_gateup11<<<2048, 512, 0, stream>>>(xb, w13b, g);
  k_down11<<<768, 512, 0, stream>>>((const unsigned short*)g, w2b, out);
}

// Round 7
// 1145.413 us; speedup vs baseline: 1.1765x; 1.0433x over previous
//
#include <hip/hip_runtime.h>
#include <hip/hip_bf16.h>

// SwiGLU FFN, fp32 in/out: out = clamp(silu(x@w1t) * (x@w3t), ±65504) @ w2t
// x[8192,3072], w13[16384,3072] (rows 0..8191 = w3 -> x3, 8192.. = w1 -> x1), w2[3072,8192].
// bf16 compute via cvt pre-pass; mfma_f32_16x16x32_bf16; fp32 accum; fp32 out.
// Round-7: gateup rebuilt on the down-proven minimal-barrier skeleton:
//   2 phases/K-tile, 2 barriers/K-tile, per-phase counted vmcnt (never drain),
//   phases split by B-matrix (B3 pass then B1 pass), A-frags read once and reused.
// Down = R5/R6-proven 1-phase/3-buf/VMCNT(6) skeleton (67% MfmaUtil), unchanged.
// 16x16x32 frags + row&7 slot swizzle everywhere (2-way LDS aliasing = free).

typedef __attribute__((ext_vector_type(8))) __bf16 bf16x8;
typedef __attribute__((ext_vector_type(4))) float f32x4;

#define GLD_LDS16(gptr, lptr)                                                        \
  __builtin_amdgcn_global_load_lds(                                                  \
      (const __attribute__((address_space(1))) void*)(gptr),                         \
      (__attribute__((address_space(3))) void*)(lptr), 16, 0, 0)

#define VMCNT(n) asm volatile("s_waitcnt vmcnt(" #n ")" ::: "memory")
#define BAR()    __builtin_amdgcn_s_barrier()

#define MFMA16(a, b, c) __builtin_amdgcn_mfma_f32_16x16x32_bf16((a), (b), (c), 0, 0, 0)

__device__ __forceinline__ __bf16 bfr(float f) {  // RNE fp32->bf16
  unsigned int u = __builtin_bit_cast(unsigned int, f);
  unsigned short r = (unsigned short)((u + 0x7FFFu + ((u >> 16) & 1u)) >> 16);
  return __builtin_bit_cast(__bf16, r);
}

// ---------------- fp32 -> bf16 conversion pre-pass ----------------
__global__ __launch_bounds__(256)
void k_cvt(const float* __restrict__ src, unsigned short* __restrict__ dst, long n) {
  long i = ((long)blockIdx.x * 256 + threadIdx.x) * 8;
  const long stride = (long)gridDim.x * 256 * 8;
  for (; i < n; i += stride) {
    float4 f0 = *(const float4*)(src + i);
    float4 f1 = *(const float4*)(src + i + 4);
    bf16x8 o;
    o[0] = bfr(f0.x); o[1] = bfr(f0.y); o[2] = bfr(f0.z); o[3] = bfr(f0.w);
    o[4] = bfr(f1.x); o[5] = bfr(f1.y); o[6] = bfr(f1.z); o[7] = bfr(f1.w);
    *(bf16x8*)(dst + i) = o;
  }
}

// ============ Kernel 1: fused gate/up, 256x128 g-tile, BK=64, 2-buf, 2-phase ============
// 8 waves (2M x 4N), per-wave 128 rows x (32 B3-cols + 32 B1-cols). 16x16x32 frags.
// Per K-tile c (buffer R=c&1, stage into S=R^1 for tile c+1):
//  PH1: VMCNT(2)  [A(c)+B3(c) landed, B1(c) in flight]; BAR; rd A-frags(16)+B3(4);
//       stage A(c+1)(4)+B3(c+1)(2); prio; 32 MFMA acc3.
//  PH2: VMCNT(6)  [B1(c) landed, A/B3(c+1) in flight]; BAR; rd B1(4);
//       stage B1(c+1)(2); prio; 32 MFMA acc1 (reuses A-frags).
__global__ __launch_bounds__(512, 2)
void k_gateup13(const unsigned short* __restrict__ X,
                const unsigned short* __restrict__ W13,
                __hip_bfloat16* __restrict__ G)
{
  constexpr int K = 3072, LDG = 8192, NT = K / 64;
  __shared__ unsigned short lds[65536];  // 128KB: 2 bufs x (A[256][64] | B3[128][64] | B1[128][64])

  const int t = threadIdx.x, l = t & 63, wid = t >> 6;
  const int wm = wid >> 2, wn = wid & 3;          // 2M x 4N
  const int l15 = l & 15, lhi = l >> 4, sw = l15 & 7;

  const int bid = blockIdx.x;                     // 2048 blocks, XCD-chunked
  const int swz = (bid & 7) * 256 + (bid >> 3);
  const int mb = swz >> 6, nb = swz & 63;

  const int srow = t >> 3;                        // 0..63
  const int scol = ((t & 7) ^ (srow & 7)) * 8;    // pre-swizzled global slot
  const unsigned short* xa = X   + (size_t)(mb * 256 + srow) * K + scol;
  const unsigned short* b3 = W13 + (size_t)(nb * 128 + srow) * K + scol;
  const unsigned short* b1 = W13 + (size_t)(8192 + nb * 128 + srow) * K + scol;
  const int lo = t * 8;

#define STG_A(d, kt) do {                                                      \
    GLD_LDS16(xa + (kt),                  lds + (d) * 32768 + lo);             \
    GLD_LDS16(xa + (size_t)64 * K + (kt),  lds + (d) * 32768 + 4096 + lo);     \
    GLD_LDS16(xa + (size_t)128 * K + (kt), lds + (d) * 32768 + 8192 + lo);     \
    GLD_LDS16(xa + (size_t)192 * K + (kt), lds + (d) * 32768 + 12288 + lo);    \
  } while (0)
#define STG_B3(d, kt) do {                                                     \
    GLD_LDS16(b3 + (kt),                 lds + (d) * 32768 + 16384 + lo);      \
    GLD_LDS16(b3 + (size_t)64 * K + (kt), lds + (d) * 32768 + 20480 + lo);     \
  } while (0)
#define STG_B1(d, kt) do {                                                     \
    GLD_LDS16(b1 + (kt),                 lds + (d) * 32768 + 24576 + lo);      \
    GLD_LDS16(b1 + (size_t)64 * K + (kt), lds + (d) * 32768 + 28672 + lo);     \
  } while (0)

  f32x4 acc3[8][2], acc1[8][2];
#pragma unroll
  for (int m = 0; m < 8; ++m)
#pragma unroll
    for (int n = 0; n < 2; ++n) {
      acc3[m][n] = (f32x4){0.f, 0.f, 0.f, 0.f};
      acc1[m][n] = (f32x4){0.f, 0.f, 0.f, 0.f};
    }

  // prologue: stage tile 0 in steady-state order [A, B3 | B1]
  STG_A(0, 0); STG_B3(0, 0); STG_B1(0, 0);

  for (int c = 0; c < NT; ++c) {
    const int R = c & 1, S = R ^ 1;
    const int kn = (c + 1 < NT ? c + 1 : 0) * 64;   // wrap keeps load count uniform
    const int Ab = R * 32768, B3b = Ab + 16384, B1b = Ab + 24576;

    // ---- PH1: A + B3 ----
    VMCNT(2);                      // A(c)+B3(c) landed; B1(c) still in flight
    BAR();                         // all waves' A/B3 landed
    bf16x8 ra[8][2], r3[2][2];
#pragma unroll
    for (int mf = 0; mf < 8; ++mf)
#pragma unroll
      for (int kk = 0; kk < 2; ++kk) {
        const int row = wm * 128 + mf * 16 + l15;
        ra[mf][kk] = *(const bf16x8*)(lds + Ab + row * 64 + ((kk * 4 + lhi) ^ sw) * 8);
      }
#pragma unroll
    for (int nf = 0; nf < 2; ++nf)
#pragma unroll
      for (int kk = 0; kk < 2; ++kk) {
        const int row = wn * 32 + nf * 16 + l15;
        r3[nf][kk] = *(const bf16x8*)(lds + B3b + row * 64 + ((kk * 4 + lhi) ^ sw) * 8);
      }
    STG_A(S, kn); STG_B3(S, kn);   // 6 loads for tile c+1 (S safe: its reads retired pre-BAR)
    __builtin_amdgcn_s_setprio(1);
#pragma unroll
    for (int mf = 0; mf < 8; ++mf)
#pragma unroll
      for (int nf = 0; nf < 2; ++nf)
#pragma unroll
        for (int kk = 0; kk < 2; ++kk)
          acc3[mf][nf] = MFMA16(ra[mf][kk], r3[nf][kk], acc3[mf][nf]);
    __builtin_amdgcn_s_setprio(0);

    // ---- PH2: B1 (A-frags reused) ----
    VMCNT(6);                      // B1(c) landed; A/B3(c+1)'s 6 in flight
    BAR();
    bf16x8 r1[2][2];
#pragma unroll
    for (int nf = 0; nf < 2; ++nf)
#pragma unroll
      for (int kk = 0; kk < 2; ++kk) {
        const int row = wn * 32 + nf * 16 + l15;
        r1[nf][kk] = *(const bf16x8*)(lds + B1b + row * 64 + ((kk * 4 + lhi) ^ sw) * 8);
      }
    STG_B1(S, kn);                 // 2 loads
    __builtin_amdgcn_s_setprio(1);
#pragma unroll
    for (int mf = 0; mf < 8; ++mf)
#pragma unroll
      for (int nf = 0; nf < 2; ++nf)
#pragma unroll
        for (int kk = 0; kk < 2; ++kk)
          acc1[mf][nf] = MFMA16(ra[mf][kk], r1[nf][kk], acc1[mf][nf]);
    __builtin_amdgcn_s_setprio(0);
  }

  // epilogue: g = clamp(silu(x1)*x3). 16x16 C/D: col=l15, row=lhi*4+r
  const int gr0 = mb * 256 + wm * 128;
  const int gc0 = nb * 128 + wn * 32;
#pragma unroll
  for (int mf = 0; mf < 8; ++mf)
#pragma unroll
    for (int nf = 0; nf < 2; ++nf)
#pragma unroll
      for (int r = 0; r < 4; ++r) {
        float h3 = acc3[mf][nf][r];
        float h1 = acc1[mf][nf][r];
        float s  = h1 / (1.f + __expf(-h1));
        float g  = fminf(fmaxf(s * h3, -65504.f), 65504.f);
        G[(size_t)(gr0 + mf * 16 + lhi * 4 + r) * LDG + (gc0 + nf * 16 + l15)] =
            __float2bfloat16(g);
      }
#undef STG_A
#undef STG_B3
#undef STG_B1
}

// ============ Kernel 2: down proj, 256x128 tile, BK=64, 3-buf, 1 phase/K-tile ============
// 8 waves (4M x 2N), per-wave 64x64, 16x16x32 frags. Proven 67% MfmaUtil — unchanged.
__global__ __launch_bounds__(512, 2)
void k_down11(const unsigned short* __restrict__ Gm,
              const unsigned short* __restrict__ W2,
              float* __restrict__ Out)
{
  constexpr int K = 8192, LDO = 3072, NT = K / 64;
  __shared__ unsigned short lds[73728];  // 144KB: A[3]@0 (16384 ea) | B[3]@49152 (8192 ea)

  const int t = threadIdx.x, l = t & 63, wid = t >> 6;
  const int wm = wid >> 1, wn = wid & 1;          // 4M x 2N
  const int l15 = l & 15, lhi = l >> 4, sw = l15 & 7;

  const int bid = blockIdx.x;                     // 768 blocks
  const int swz = (bid & 7) * 96 + (bid >> 3);
  const int mb = swz / 24, nb = swz % 24;

  const int srow = t >> 3;
  const int scol = ((t & 7) ^ (srow & 7)) * 8;
  const unsigned short* ga = Gm + (size_t)(mb * 256 + srow) * K + scol;
  const unsigned short* wb = W2 + (size_t)(nb * 128 + srow) * K + scol;
  const int lo = t * 8;

#define DST_A(e, kt) do {                                                       \
    GLD_LDS16(ga + (kt),                 lds + (e) * 16384 + lo);               \
    GLD_LDS16(ga + (size_t)64 * K + (kt),  lds + (e) * 16384 + 4096 + lo);      \
    GLD_LDS16(ga + (size_t)128 * K + (kt), lds + (e) * 16384 + 8192 + lo);      \
    GLD_LDS16(ga + (size_t)192 * K + (kt), lds + (e) * 16384 + 12288 + lo);     \
  } while (0)
#define DST_B(e, kt) do {                                                       \
    GLD_LDS16(wb + (kt),                lds + 49152 + (e) * 8192 + lo);         \
    GLD_LDS16(wb + (size_t)64 * K + (kt), lds + 49152 + (e) * 8192 + 4096 + lo); \
  } while (0)

  f32x4 acc[4][4];
#pragma unroll
  for (int mf = 0; mf < 4; ++mf)
#pragma unroll
    for (int nf = 0; nf < 4; ++nf)
      acc[mf][nf] = (f32x4){0.f, 0.f, 0.f, 0.f};

  // prologue: tiles 0,1 (6 loads each)
  DST_B(0, 0);  DST_A(0, 0);
  DST_B(1, 64); DST_A(1, 64);

  for (int c = 0; c < NT; ++c) {
    const int e = c % 3;
    const int eS = (c + 2) % 3;
    const int k2 = (c + 2 < NT ? c + 2 : 0) * 64;

    VMCNT(6);    // tile c's 6 landed (tile c+1's 6 in flight)
    BAR();

    bf16x8 ra[4][2], rb[4][2];
#pragma unroll
    for (int mf = 0; mf < 4; ++mf)
#pragma unroll
      for (int kk = 0; kk < 2; ++kk)
        ra[mf][kk] = *(const bf16x8*)(lds + e * 16384 + (wm * 64 + mf * 16 + l15) * 64 + ((kk * 4 + lhi) ^ sw) * 8);
#pragma unroll
    for (int nf = 0; nf < 4; ++nf)
#pragma unroll
      for (int kk = 0; kk < 2; ++kk)
        rb[nf][kk] = *(const bf16x8*)(lds + 49152 + e * 8192 + (wn * 64 + nf * 16 + l15) * 64 + ((kk * 4 + lhi) ^ sw) * 8);

    // stage tile c+2 into buffer of tile c-1 (reads done before this iter's barrier)
    DST_B(eS, k2);
    DST_A(eS, k2);

    __builtin_amdgcn_s_setprio(1);
#pragma unroll
    for (int mf = 0; mf < 4; ++mf)
#pragma unroll
      for (int nf = 0; nf < 4; ++nf)
#pragma unroll
        for (int kk = 0; kk < 2; ++kk)
          acc[mf][nf] = MFMA16(ra[mf][kk], rb[nf][kk], acc[mf][nf]);
    __builtin_amdgcn_s_setprio(0);
  }

  const int r0 = mb * 256 + wm * 64;
  const int c0 = nb * 128 + wn * 64;
#pragma unroll
  for (int mf = 0; mf < 4; ++mf)
#pragma unroll
    for (int nf = 0; nf < 4; ++nf)
#pragma unroll
      for (int r = 0; r < 4; ++r)
        Out[(size_t)(r0 + mf * 16 + lhi * 4 + r) * LDO + (c0 + nf * 16 + l15)] =
            acc[mf][nf][r];
#undef DST_A
#undef DST_B
}

extern "C" void kernel_launch(void* const* d_in, const int* in_sizes, int n_in,
                              void* d_out, int out_size, void* d_ws, size_t ws_size,
                              hipStream_t stream) {
  const float* x   = (const float*)d_in[0];   // [2,4096,3072] f32
  const float* w13 = (const float*)d_in[1];   // [16384,3072] f32
  const float* w2  = (const float*)d_in[2];   // [3072,8192] f32
  float* out = (float*)d_out;                 // [2,4096,3072] f32

  const long NX = 25165824L, NW13 = 50331648L, NW2 = 25165824L;
  const size_t XB = 50331648, W13B = 100663296, W2B = 50331648;

  unsigned short* xb   = (unsigned short*)d_ws;
  unsigned short* w13b = (unsigned short*)((char*)d_ws + XB);
  unsigned short* w2b  = (unsigned short*)((char*)d_ws + XB + W13B);
  __hip_bfloat16* g    = (__hip_bfloat16*)((char*)d_ws + XB + W13B + W2B);

  k_cvt<<<2048, 256, 0, stream>>>(x,   xb,   NX);
  k_cvt<<<2048, 256, 0, stream>>>(w13, w13b, NW13);
  k_cvt<<<2048, 256, 0, stream>>>(w2,  w2b,  NW2);
  k_gateup13<<<2048, 512, 0, stream>>>(xb, w13b, g);
  k_down11<<<768, 512, 0, stream>>>((const unsigned short*)g, w2b, out);
}